// Round 7
// baseline (1302.606 us; speedup 1.0000x reference)
//
#include <hip/hip_runtime.h>

// Sizes (fixed for this problem)
constexpr int B  = 2,  CIN = 2,  H = 64, W = 64, T = 350;
constexpr int C1 = 8;                       // conv1 out channels
constexpr int TO = 700, HO = 128, WO = 64;
constexpr int HW = H * W;                   // 4096

#define DEC 0.05000000074505806f            // (float)(1.0 - 0.95)

// ---------------------------------------------------------------------------
// Kernel 0: transpose x [B,2,H,W,T] -> xT [B,2,T,H,W] so conv reads coalesce.
// ---------------------------------------------------------------------------
__global__ void __launch_bounds__(256) transpose_kernel(
    const float* __restrict__ x, float* __restrict__ xT) {
  __shared__ float tile[64][65];
  int bid   = blockIdx.x;
  int tTile = bid % 6;            // 6 tiles of 64 cover T=350
  int slice = bid / 6;            // (b*2+ci)*64 + h
  int h  = slice % H;
  int bc = slice / H;             // b*2+ci
  int t0 = tTile * 64;
  int tx = threadIdx.x & 63;
  int tz = threadIdx.x >> 6;      // 0..3

  const float* src = x + ((long)bc * H + h) * (long)(W * T);
#pragma unroll
  for (int i = 0; i < 16; ++i) {
    int w = tz * 16 + i;
    int t = t0 + tx;
    tile[w][tx] = (t < T) ? src[(long)w * T + t] : 0.0f;
  }
  __syncthreads();
  float* dst = xT + ((long)bc * T) * HW + h * 64;
#pragma unroll
  for (int i = 0; i < 16; ++i) {
    int tl = tz * 16 + i;
    int t  = t0 + tl;
    if (t < T) dst[(long)t * HW + tx] = tile[tx][tl];
  }
}

// ---------------------------------------------------------------------------
// async global->LDS, 16 bytes per lane (wave-uniform LDS base + lane*16)
// ---------------------------------------------------------------------------
__device__ __forceinline__ void gload_lds16(const float* g, float* l) {
  __builtin_amdgcn_global_load_lds(
      (const __attribute__((address_space(1))) unsigned int*)g,
      (__attribute__((address_space(3))) unsigned int*)l, 16, 0, 0);
}

// ---------------------------------------------------------------------------
// Kernel A: conv1(5x5 over T,H) + bias + relu + LIF1 + delta -> d8 int8
// d8 layout: [b][t][hw][ci]  (ci contiguous -> stage2 loads 8B per thread)
// block = 512 = (co 0..7) x (w 0..63); grid (b,h,chunk of 6) = 768 = 3/CU.
// Superstep S=5. Each LDS buffer: 64 rows x 64 floats (rows 0..49 = taus,
// rows 50..63 = pad WRITTEN BY STAGING (r6 bug: pad must live inside the
// buffer!)). 2 issues x 32 rows per superstep; counted vmcnt(2).
// Spikes: ds_write_b8 into double-buffered st[2][5][512]; flushed one
// superstep later (after barrier-2) as coalesced uint4 stores so the store
// never gates vmcnt(2). lgkmcnt(0) before every publishing barrier.
// LDS total 37.9KB; VGPR<=85 (launch_bounds 512,6) -> 3 blocks/CU.
// ---------------------------------------------------------------------------
__global__ void __launch_bounds__(512, 6) convlif_kernel(
    const float* __restrict__ xT, const float* __restrict__ w1,
    const float* __restrict__ b1, signed char* __restrict__ d8) {
  __shared__ float buf[2][64 * 64];                     // 2 x 16 KiB
  __shared__ __align__(16) unsigned char st[2][5][512]; // 5 KiB, dbuf spikes
  const int tid = threadIdx.x;
  const int bid = blockIdx.x;
  const int chunk = bid % 6;
  const int rest  = bid / 6;
  const int h = rest & 63;
  const int b = rest >> 6;
  const int w  = tid & 63;
  const int co = tid >> 6;                  // == wave id

  // Weights for this co; zero rows whose h+dh-2 is out of range.
  float wt[2][5][5];
#pragma unroll
  for (int ci = 0; ci < 2; ++ci)
#pragma unroll
    for (int dt = 0; dt < 5; ++dt)
#pragma unroll
      for (int dh = 0; dh < 5; ++dh)
        wt[ci][dt][dh] = w1[((co * 2 + ci) * 5 + dt) * 5 + dh];
  float bias = b1[co];

  // Clamped row bases for the one-time window init (global reads).
  const float* basep[2][5];
#pragma unroll
  for (int ci = 0; ci < 2; ++ci)
#pragma unroll
    for (int dh = 0; dh < 5; ++dh) {
      int hh = h + dh - 2;
      bool hv = (hh >= 0) && (hh < H);
      int hc = hh < 0 ? 0 : (hh > H - 1 ? H - 1 : hh);
      basep[ci][dh] = xT + ((long)((b * 2 + ci) * T)) * HW + hc * 64 + w;
      if (!hv) {
#pragma unroll
        for (int dt = 0; dt < 5; ++dt) wt[ci][dt][dh] = 0.0f;
      }
    }

  // Staging descriptors: 2 issues x 32 rows; row r -> (tau_loc, ci, dh).
  // LDS dest rows = i*32 + co*4 + (lane>>4) in [0,63] -- always in-buffer.
  int tloc[2];
  int cpart[2];
#pragma unroll
  for (int i = 0; i < 2; ++i) {
    int r = (tid >> 4) + 32 * i;
    if (r > 49) r = 49;                     // clamp SOURCE only (rows 50..63 pad)
    int tl  = r / 10;
    int rem = r - tl * 10;
    int ci  = rem / 5;
    int dh  = rem - ci * 5;
    int hh = h + dh - 2;
    int hc = hh < 0 ? 0 : (hh > H - 1 ? H - 1 : hh);
    tloc[i]  = tl;
    cpart[i] = ((b * 2 + ci) * T) * HW + hc * 64 + (tid & 15) * 4;
  }

  // chunk c of 6: stored [60c, min(60c+60,350)); 15-step warm-up before.
  const int tstore = chunk * 60;
  const int ts     = chunk ? tstore - 15 : 0;   // multiple of 5
  const int te     = tstore + 60 < T ? tstore + 60 : T;
  const int nsup   = (te - ts) / 5;             // 12 / 15 / 13

  // Prologue: stage buffer 0 (taus ts+3 .. ts+7).
  {
    int bs = ts + 3;
#pragma unroll
    for (int i = 0; i < 2; ++i) {
      int tau = bs + tloc[i];
      if (tau > T - 1) tau = T - 1;
      gload_lds16(xT + (long)cpart[i] + (long)tau * HW,
                  &buf[0][(i * 32 + co * 4) * 64]);
    }
  }

  // Init sliding window (taus ts-2..ts+2); slot = tau mod 5 (ts%5==0).
  float win[2][5][5];
#pragma unroll
  for (int ci = 0; ci < 2; ++ci)
#pragma unroll
    for (int dh = 0; dh < 5; ++dh) {
      const float* bp = basep[ci][dh];
      win[ci][dh][3] = (ts >= 2) ? bp[(long)(ts - 2) * HW] : 0.0f;
      win[ci][dh][4] = (ts >= 1) ? bp[(long)(ts - 1) * HW] : 0.0f;
      win[ci][dh][0] = bp[(long)(ts + 0) * HW];
      win[ci][dh][1] = bp[(long)(ts + 1) * HW];
      win[ci][dh][2] = bp[(long)(ts + 2) * HW];
    }

  asm volatile("s_waitcnt vmcnt(0)" ::: "memory");
  __builtin_amdgcn_s_barrier();
  asm volatile("" ::: "memory");

  signed char* const d8row = d8 + ((long)(b * T)) * (HW * C1) + h * 512;
  const int fl_u  = tid >> 5;               // flush row (0..4) for tid<160
  const int fl_cb = (tid & 31) * 16;        // flush byte offset within row
  const int stw   = w * 8 + co;             // this thread's spike byte slot

  float y = 0.0f, sprev = 0.0f;
  for (int k = 0; k < nsup; ++k) {
    // barrier1: publish st[(k-1)&1] writes + ensure buf[(k+1)&1] readers done
    asm volatile("s_waitcnt lgkmcnt(0)" ::: "memory");
    __builtin_amdgcn_s_barrier();
    asm volatile("" ::: "memory");

    if (k + 1 < nsup) {
      int bs = ts + 3 + 5 * (k + 1);
      float* nb = &buf[(k + 1) & 1][0];
#pragma unroll
      for (int i = 0; i < 2; ++i) {
        int tau = bs + tloc[i];
        if (tau > T - 1) tau = T - 1;
        gload_lds16(xT + (long)cpart[i] + (long)tau * HW,
                    nb + (i * 32 + co * 4) * 64);
      }
      asm volatile("s_waitcnt vmcnt(2)" ::: "memory");   // my buf[k&1] retired
    } else {
      asm volatile("s_waitcnt vmcnt(0)" ::: "memory");
    }
    __builtin_amdgcn_s_barrier();           // barrier2: buf[k&1] ready for all
    asm volatile("" ::: "memory");

    float* lb = &buf[k & 1][0];
    {
      // zero rows whose tau >= T (only final supersteps of last chunk)
      int bufstart = ts + 3 + 5 * k;
      int rz0 = (T - bufstart) * 10;
      if (rz0 < 50) {
        if (rz0 < 0) rz0 = 0;
        for (int r = rz0 + co; r < 50; r += 8) lb[r * 64 + w] = 0.0f;
        asm volatile("s_waitcnt lgkmcnt(0)" ::: "memory");
        __builtin_amdgcn_s_barrier();
        asm volatile("" ::: "memory");
      }
    }

    // Flush superstep k-1's spikes (other st buffer; store has a full
    // superstep to retire before it reaches vmcnt(2)'s drain window).
    if (k > 0 && tid < 160) {
      int t = ts + 5 * (k - 1) + fl_u;
      if (t >= tstore && t < te) {
        const unsigned char* sp = &st[(k - 1) & 1][0][0];
        uint4 v = *reinterpret_cast<const uint4*>(sp + fl_u * 512 + fl_cb);
        *reinterpret_cast<uint4*>(d8row + (long)t * (HW * C1) + fl_cb) = v;
      }
    }

    unsigned char* stk = &st[k & 1][0][0];
    const int t0s = ts + 5 * k;
#pragma unroll
    for (int u = 0; u < 5; ++u) {
      int t = t0s + u;
      float ac0 = 0.f, ac1 = 0.f, ac2 = 0.f, ac3 = 0.f;
#pragma unroll
      for (int ci = 0; ci < 2; ++ci)
#pragma unroll
        for (int dt = 0; dt < 5; ++dt) {
          const int slot = (u + dt + 3) % 5;
#pragma unroll
          for (int dh = 0; dh < 5; ++dh) {
            const int q = (ci * 25 + dt * 5 + dh) & 3;
            float p = win[ci][dh][slot] * wt[ci][dt][dh];
            if (q == 0) ac0 += p;
            else if (q == 1) ac1 += p;
            else if (q == 2) ac2 += p;
            else ac3 += p;
          }
        }
      float a = ((ac0 + ac1) + (ac2 + ac3)) + bias;
      a = fmaxf(a, 0.0f);
      y = fmaf(DEC, y, a);
      float s = (y >= 1.0f) ? 1.0f : 0.0f;
      float dlt = (t == 0) ? 0.0f : (s - sprev);
      stk[u * 512 + stw] = (unsigned char)(signed char)dlt;
      sprev = s;
      y = (s != 0.0f) ? 0.0f : y;
      // slide: tau = t+3 lives at LDS row (u*10 + ci*5 + dh)
      const int slot2 = (u + 3) % 5;
#pragma unroll
      for (int ci = 0; ci < 2; ++ci)
#pragma unroll
        for (int dh = 0; dh < 5; ++dh)
          win[ci][dh][slot2] = lb[(u * 10 + ci * 5 + dh) * 64 + w];
    }
  }

  // Epilogue flush: last superstep's spikes.
  asm volatile("s_waitcnt lgkmcnt(0)" ::: "memory");
  __builtin_amdgcn_s_barrier();
  asm volatile("" ::: "memory");
  if (tid < 160) {
    int t = ts + 5 * (nsup - 1) + fl_u;
    if (t >= tstore && t < te) {
      const unsigned char* sp = &st[(nsup - 1) & 1][0][0];
      uint4 v = *reinterpret_cast<const uint4*>(sp + fl_u * 512 + fl_cb);
      *reinterpret_cast<uint4*>(d8row + (long)t * (HW * C1) + fl_cb) = v;
    }
  }
}

// ---------------------------------------------------------------------------
// Kernel B: deconv(2x2,s2) + bias + relu + conv2(1x1) + LIF2 -> out
// d8 [b][t][hw][ci]: one 8B uint2 load per pair-step, prefetched 1 iter ahead.
// out layout [B,2,H',W',T']; LDS-staged transposed flush. 16 chunks.
// (unchanged from round 5 -- passed)
// ---------------------------------------------------------------------------
__global__ void __launch_bounds__(64) stage2_kernel(
    const signed char* __restrict__ d8, const float* __restrict__ dw,
    const float* __restrict__ db, const float* __restrict__ cw,
    const float* __restrict__ cb, float* __restrict__ out) {
  __shared__ float SB[2][64][17];
  int bid   = blockIdx.x;
  int chunk = bid & 15;           // 16 chunks over T'=700
  int rest  = bid >> 4;
  int hp = rest & 127;            // h'
  int b  = rest >> 7;
  int wp = threadIdx.x;           // w'

  int h  = hp >> 1;
  int kh = 1 - (hp & 1);

  // deconv weights for this kh, both kt parities: dwk{kt}[c][ci]
  float dwk0[2][8], dwk1[2][8];
#pragma unroll
  for (int c = 0; c < 2; ++c)
#pragma unroll
    for (int ci = 0; ci < 8; ++ci) {
      dwk0[c][ci] = dw[((c * 8 + ci) * 2 + 0) * 2 + kh];
      dwk1[c][ci] = dw[((c * 8 + ci) * 2 + 1) * 2 + kh];
    }
  float db0 = db[0], db1 = db[1];
  float cw00 = cw[0], cw01 = cw[1], cw10 = cw[2], cw11 = cw[3];
  float cb0 = cb[0], cb1 = cb[1];

  int t0 = chunk * 44;
  int t1 = (t0 + 44 < TO) ? t0 + 44 : TO;   // last chunk: 40
  int tw = (t0 - 16 > 0) ? t0 - 16 : 0;     // 16-step LIF2 warm-up (even)

  const signed char* dbase = d8 + (((long)b * T) * HW + h * 64 + wp) * C1;
  const long tstride = (long)HW * C1;       // bytes per t
  float* outb = out + ((long)b * 2 * HO) * (long)(WO * TO);

  float y0 = 0.0f, y1 = 0.0f;
  uint2 dc = *reinterpret_cast<const uint2*>(dbase + (long)(tw >> 1) * tstride);
  for (int tp = tw; tp < t1; tp += 2) {
    int tn = (tp + 2 < t1) ? ((tp + 2) >> 1) : ((t1 - 1) >> 1);
    uint2 dn = *reinterpret_cast<const uint2*>(dbase + (long)tn * tstride);

    float dv[8];
#pragma unroll
    for (int ci = 0; ci < 4; ++ci) {
      dv[ci]     = (float)(signed char)((dc.x >> (8 * ci)) & 0xff);
      dv[ci + 4] = (float)(signed char)((dc.y >> (8 * ci)) & 0xff);
    }

#pragma unroll
    for (int par = 0; par < 2; ++par) {     // par=0: tp (kt=1), par=1: tp+1 (kt=0)
      int tpp = tp + par;
      float v0 = db0, v1 = db1;
      if (par == 0) {
#pragma unroll
        for (int ci = 0; ci < 8; ++ci) {
          v0 = fmaf(dv[ci], dwk1[0][ci], v0);
          v1 = fmaf(dv[ci], dwk1[1][ci], v1);
        }
      } else {
#pragma unroll
        for (int ci = 0; ci < 8; ++ci) {
          v0 = fmaf(dv[ci], dwk0[0][ci], v0);
          v1 = fmaf(dv[ci], dwk0[1][ci], v1);
        }
      }
      v0 = fmaxf(v0, 0.0f);
      v1 = fmaxf(v1, 0.0f);
      float u0 = fmaf(cw00, v0, fmaf(cw01, v1, cb0));
      float u1 = fmaf(cw10, v0, fmaf(cw11, v1, cb1));
      y0 = fmaf(DEC, y0, u0);
      y1 = fmaf(DEC, y1, u1);
      float s0 = (y0 >= 1.0f) ? 1.0f : 0.0f;
      float s1 = (y1 >= 1.0f) ? 1.0f : 0.0f;
      y0 = (s0 != 0.0f) ? 0.0f : y0;
      y1 = (s1 != 0.0f) ? 0.0f : y1;

      if (tpp >= t0) {
        int k = (tpp - t0) & 15;
        SB[0][wp][k] = s0;
        SB[1][wp][k] = s1;
        if (par == 1 && (k == 15 || tpp == t1 - 1)) {
          __syncthreads();
          int Kc  = k + 1;                  // 16 or a multiple of 4
          int t0f = tpp - k;
#pragma unroll
          for (int o = 0; o < 2; ++o) {
            float* ob = outb + ((long)(o * HO + hp)) * (long)(WO * TO);
#pragma unroll
            for (int i = 0; i < 4; ++i) {
              int idx = (i << 6) + wp;
              int r   = idx >> 2;
              int c   = (idx & 3) << 2;
              if (c < Kc) {
                float4 vv;
                vv.x = SB[o][r][c + 0];
                vv.y = SB[o][r][c + 1];
                vv.z = SB[o][r][c + 2];
                vv.w = SB[o][r][c + 3];
                *reinterpret_cast<float4*>(ob + (long)r * TO + (t0f + c)) = vv;
              }
            }
          }
          __syncthreads();
        }
      }
    }
    dc = dn;
  }
}

// ---------------------------------------------------------------------------
extern "C" void kernel_launch(void* const* d_in, const int* in_sizes, int n_in,
                              void* d_out, int out_size, void* d_ws, size_t ws_size,
                              hipStream_t stream) {
  const float* x  = (const float*)d_in[0];
  const float* w1 = (const float*)d_in[1];
  const float* b1 = (const float*)d_in[2];
  const float* dw = (const float*)d_in[3];
  const float* db = (const float*)d_in[4];
  const float* cw = (const float*)d_in[5];
  const float* cb = (const float*)d_in[6];
  float* out = (float*)d_out;

  float* xT = (float*)d_ws;                                   // 22.94 MB
  signed char* d8 = (signed char*)d_ws + (size_t)B * CIN * T * HW * 4;  // +22.94 MB

  // 1) transpose x -> xT
  transpose_kernel<<<dim3(B * CIN * H * 6), dim3(256), 0, stream>>>(x, xT);
  // 2) conv1+relu+LIF1+delta -> d8 (6 T-chunks, S=5 LDS pipeline, 3 blocks/CU)
  convlif_kernel<<<dim3(B * H * 6), dim3(512), 0, stream>>>(xT, w1, b1, d8);
  // 3) deconv+relu+conv2+LIF2 -> out (16 T'-chunks, uint2 prefetch)
  stage2_kernel<<<dim3(B * HO * 16), dim3(64), 0, stream>>>(d8, dw, db, cw, cb, out);
}

// Round 8
// 131.316 us; speedup vs baseline: 9.9196x; 9.9196x over previous
//
#include <hip/hip_runtime.h>

// Sizes (fixed for this problem)
constexpr int B  = 2,  CIN = 2,  H = 64, W = 64, T = 350;
constexpr int C1 = 8;                       // conv1 out channels
constexpr int TO = 700, HO = 128, WO = 64;
constexpr int HW = H * W;                   // 4096

#define DEC 0.05000000074505806f            // (float)(1.0 - 0.95)

// ---------------------------------------------------------------------------
// Kernel 0: transpose x [B,2,H,W,T] -> xT [B,2,T,H,W] so conv reads coalesce.
// ---------------------------------------------------------------------------
__global__ void __launch_bounds__(256) transpose_kernel(
    const float* __restrict__ x, float* __restrict__ xT) {
  __shared__ float tile[64][65];
  int bid   = blockIdx.x;
  int tTile = bid % 6;            // 6 tiles of 64 cover T=350
  int slice = bid / 6;            // (b*2+ci)*64 + h
  int h  = slice % H;
  int bc = slice / H;             // b*2+ci
  int t0 = tTile * 64;
  int tx = threadIdx.x & 63;
  int tz = threadIdx.x >> 6;      // 0..3

  const float* src = x + ((long)bc * H + h) * (long)(W * T);
#pragma unroll
  for (int i = 0; i < 16; ++i) {
    int w = tz * 16 + i;
    int t = t0 + tx;
    tile[w][tx] = (t < T) ? src[(long)w * T + t] : 0.0f;
  }
  __syncthreads();
  float* dst = xT + ((long)bc * T) * HW + h * 64;
#pragma unroll
  for (int i = 0; i < 16; ++i) {
    int tl = tz * 16 + i;
    int t  = t0 + tl;
    if (t < T) dst[(long)t * HW + tx] = tile[tx][tl];
  }
}

// ---------------------------------------------------------------------------
// async global->LDS, 16 bytes per lane (wave-uniform LDS base + lane*16)
// ---------------------------------------------------------------------------
__device__ __forceinline__ void gload_lds16(const float* g, float* l) {
  __builtin_amdgcn_global_load_lds(
      (const __attribute__((address_space(1))) unsigned int*)g,
      (__attribute__((address_space(3))) unsigned int*)l, 16, 0, 0);
}

// ---------------------------------------------------------------------------
// Kernel A: conv1(5x5 over T,H) + bias + relu + LIF1 + delta -> d8 int8
// d8 layout: [b][t][hw][ci]  (ci contiguous -> stage2 loads 8B per thread)
// block = 512 = (co 0..7) x (w 0..63); grid (b,h,chunk of 6) = 768 = 3/CU.
// Superstep S=5; 64-row double-buffered input staging (pad rows in-buffer);
// double-buffered LDS spike staging flushed as coalesced uint4 stores.
// IDENTICAL to round 7 except: NO second __launch_bounds__ arg. The (512,6)
// cap crushed VGPR 76->40 and spilled win[] to scratch (5.4 GB of traffic,
// VALUBusy 4.7%). Occupancy must come from LDS size (37.9KB -> 3+ blocks/CU
// at natural ~76 VGPR <= 85 = 512/6), never from a VGPR cap.
// ---------------------------------------------------------------------------
__global__ void __launch_bounds__(512) convlif_kernel(
    const float* __restrict__ xT, const float* __restrict__ w1,
    const float* __restrict__ b1, signed char* __restrict__ d8) {
  __shared__ float buf[2][64 * 64];                     // 2 x 16 KiB
  __shared__ __align__(16) unsigned char st[2][5][512]; // 5 KiB, dbuf spikes
  const int tid = threadIdx.x;
  const int bid = blockIdx.x;
  const int chunk = bid % 6;
  const int rest  = bid / 6;
  const int h = rest & 63;
  const int b = rest >> 6;
  const int w  = tid & 63;
  const int co = tid >> 6;                  // == wave id

  // Weights for this co; zero rows whose h+dh-2 is out of range.
  float wt[2][5][5];
#pragma unroll
  for (int ci = 0; ci < 2; ++ci)
#pragma unroll
    for (int dt = 0; dt < 5; ++dt)
#pragma unroll
      for (int dh = 0; dh < 5; ++dh)
        wt[ci][dt][dh] = w1[((co * 2 + ci) * 5 + dt) * 5 + dh];
  float bias = b1[co];

  // Clamped row bases for the one-time window init (global reads).
  const float* basep[2][5];
#pragma unroll
  for (int ci = 0; ci < 2; ++ci)
#pragma unroll
    for (int dh = 0; dh < 5; ++dh) {
      int hh = h + dh - 2;
      bool hv = (hh >= 0) && (hh < H);
      int hc = hh < 0 ? 0 : (hh > H - 1 ? H - 1 : hh);
      basep[ci][dh] = xT + ((long)((b * 2 + ci) * T)) * HW + hc * 64 + w;
      if (!hv) {
#pragma unroll
        for (int dt = 0; dt < 5; ++dt) wt[ci][dt][dh] = 0.0f;
      }
    }

  // Staging descriptors: 2 issues x 32 rows; row r -> (tau_loc, ci, dh).
  // LDS dest rows = i*32 + co*4 + (lane>>4) in [0,63] -- always in-buffer.
  int tloc[2];
  int cpart[2];
#pragma unroll
  for (int i = 0; i < 2; ++i) {
    int r = (tid >> 4) + 32 * i;
    if (r > 49) r = 49;                     // clamp SOURCE only (rows 50..63 pad)
    int tl  = r / 10;
    int rem = r - tl * 10;
    int ci  = rem / 5;
    int dh  = rem - ci * 5;
    int hh = h + dh - 2;
    int hc = hh < 0 ? 0 : (hh > H - 1 ? H - 1 : hh);
    tloc[i]  = tl;
    cpart[i] = ((b * 2 + ci) * T) * HW + hc * 64 + (tid & 15) * 4;
  }

  // chunk c of 6: stored [60c, min(60c+60,350)); 15-step warm-up before.
  const int tstore = chunk * 60;
  const int ts     = chunk ? tstore - 15 : 0;   // multiple of 5
  const int te     = tstore + 60 < T ? tstore + 60 : T;
  const int nsup   = (te - ts) / 5;             // 12 / 15 / 13

  // Prologue: stage buffer 0 (taus ts+3 .. ts+7).
  {
    int bs = ts + 3;
#pragma unroll
    for (int i = 0; i < 2; ++i) {
      int tau = bs + tloc[i];
      if (tau > T - 1) tau = T - 1;
      gload_lds16(xT + (long)cpart[i] + (long)tau * HW,
                  &buf[0][(i * 32 + co * 4) * 64]);
    }
  }

  // Init sliding window (taus ts-2..ts+2); slot = tau mod 5 (ts%5==0).
  float win[2][5][5];
#pragma unroll
  for (int ci = 0; ci < 2; ++ci)
#pragma unroll
    for (int dh = 0; dh < 5; ++dh) {
      const float* bp = basep[ci][dh];
      win[ci][dh][3] = (ts >= 2) ? bp[(long)(ts - 2) * HW] : 0.0f;
      win[ci][dh][4] = (ts >= 1) ? bp[(long)(ts - 1) * HW] : 0.0f;
      win[ci][dh][0] = bp[(long)(ts + 0) * HW];
      win[ci][dh][1] = bp[(long)(ts + 1) * HW];
      win[ci][dh][2] = bp[(long)(ts + 2) * HW];
    }

  asm volatile("s_waitcnt vmcnt(0)" ::: "memory");
  __builtin_amdgcn_s_barrier();
  asm volatile("" ::: "memory");

  signed char* const d8row = d8 + ((long)(b * T)) * (HW * C1) + h * 512;
  const int fl_u  = tid >> 5;               // flush row (0..4) for tid<160
  const int fl_cb = (tid & 31) * 16;        // flush byte offset within row
  const int stw   = w * 8 + co;             // this thread's spike byte slot

  float y = 0.0f, sprev = 0.0f;
  for (int k = 0; k < nsup; ++k) {
    // barrier1: publish st[(k-1)&1] writes + ensure buf[(k+1)&1] readers done
    asm volatile("s_waitcnt lgkmcnt(0)" ::: "memory");
    __builtin_amdgcn_s_barrier();
    asm volatile("" ::: "memory");

    if (k + 1 < nsup) {
      int bs = ts + 3 + 5 * (k + 1);
      float* nb = &buf[(k + 1) & 1][0];
#pragma unroll
      for (int i = 0; i < 2; ++i) {
        int tau = bs + tloc[i];
        if (tau > T - 1) tau = T - 1;
        gload_lds16(xT + (long)cpart[i] + (long)tau * HW,
                    nb + (i * 32 + co * 4) * 64);
      }
      asm volatile("s_waitcnt vmcnt(2)" ::: "memory");   // my buf[k&1] retired
    } else {
      asm volatile("s_waitcnt vmcnt(0)" ::: "memory");
    }
    __builtin_amdgcn_s_barrier();           // barrier2: buf[k&1] ready for all
    asm volatile("" ::: "memory");

    float* lb = &buf[k & 1][0];
    {
      // zero rows whose tau >= T (only final supersteps of last chunk)
      int bufstart = ts + 3 + 5 * k;
      int rz0 = (T - bufstart) * 10;
      if (rz0 < 50) {
        if (rz0 < 0) rz0 = 0;
        for (int r = rz0 + co; r < 50; r += 8) lb[r * 64 + w] = 0.0f;
        asm volatile("s_waitcnt lgkmcnt(0)" ::: "memory");
        __builtin_amdgcn_s_barrier();
        asm volatile("" ::: "memory");
      }
    }

    // Flush superstep k-1's spikes (other st buffer; store has a full
    // superstep to retire before it reaches vmcnt(2)'s drain window).
    if (k > 0 && tid < 160) {
      int t = ts + 5 * (k - 1) + fl_u;
      if (t >= tstore && t < te) {
        const unsigned char* sp = &st[(k - 1) & 1][0][0];
        uint4 v = *reinterpret_cast<const uint4*>(sp + fl_u * 512 + fl_cb);
        *reinterpret_cast<uint4*>(d8row + (long)t * (HW * C1) + fl_cb) = v;
      }
    }

    unsigned char* stk = &st[k & 1][0][0];
    const int t0s = ts + 5 * k;
#pragma unroll
    for (int u = 0; u < 5; ++u) {
      int t = t0s + u;
      float ac0 = 0.f, ac1 = 0.f, ac2 = 0.f, ac3 = 0.f;
#pragma unroll
      for (int ci = 0; ci < 2; ++ci)
#pragma unroll
        for (int dt = 0; dt < 5; ++dt) {
          const int slot = (u + dt + 3) % 5;
#pragma unroll
          for (int dh = 0; dh < 5; ++dh) {
            const int q = (ci * 25 + dt * 5 + dh) & 3;
            float p = win[ci][dh][slot] * wt[ci][dt][dh];
            if (q == 0) ac0 += p;
            else if (q == 1) ac1 += p;
            else if (q == 2) ac2 += p;
            else ac3 += p;
          }
        }
      float a = ((ac0 + ac1) + (ac2 + ac3)) + bias;
      a = fmaxf(a, 0.0f);
      y = fmaf(DEC, y, a);
      float s = (y >= 1.0f) ? 1.0f : 0.0f;
      float dlt = (t == 0) ? 0.0f : (s - sprev);
      stk[u * 512 + stw] = (unsigned char)(signed char)dlt;
      sprev = s;
      y = (s != 0.0f) ? 0.0f : y;
      // slide: tau = t+3 lives at LDS row (u*10 + ci*5 + dh)
      const int slot2 = (u + 3) % 5;
#pragma unroll
      for (int ci = 0; ci < 2; ++ci)
#pragma unroll
        for (int dh = 0; dh < 5; ++dh)
          win[ci][dh][slot2] = lb[(u * 10 + ci * 5 + dh) * 64 + w];
    }
  }

  // Epilogue flush: last superstep's spikes.
  asm volatile("s_waitcnt lgkmcnt(0)" ::: "memory");
  __builtin_amdgcn_s_barrier();
  asm volatile("" ::: "memory");
  if (tid < 160) {
    int t = ts + 5 * (nsup - 1) + fl_u;
    if (t >= tstore && t < te) {
      const unsigned char* sp = &st[(nsup - 1) & 1][0][0];
      uint4 v = *reinterpret_cast<const uint4*>(sp + fl_u * 512 + fl_cb);
      *reinterpret_cast<uint4*>(d8row + (long)t * (HW * C1) + fl_cb) = v;
    }
  }
}

// ---------------------------------------------------------------------------
// Kernel B: deconv(2x2,s2) + bias + relu + conv2(1x1) + LIF2 -> out
// d8 [b][t][hw][ci]: one 8B uint2 load per pair-step, prefetched 1 iter ahead.
// out layout [B,2,H',W',T']; LDS-staged transposed flush. 16 chunks.
// (unchanged -- passed in rounds 5-7)
// ---------------------------------------------------------------------------
__global__ void __launch_bounds__(64) stage2_kernel(
    const signed char* __restrict__ d8, const float* __restrict__ dw,
    const float* __restrict__ db, const float* __restrict__ cw,
    const float* __restrict__ cb, float* __restrict__ out) {
  __shared__ float SB[2][64][17];
  int bid   = blockIdx.x;
  int chunk = bid & 15;           // 16 chunks over T'=700
  int rest  = bid >> 4;
  int hp = rest & 127;            // h'
  int b  = rest >> 7;
  int wp = threadIdx.x;           // w'

  int h  = hp >> 1;
  int kh = 1 - (hp & 1);

  // deconv weights for this kh, both kt parities: dwk{kt}[c][ci]
  float dwk0[2][8], dwk1[2][8];
#pragma unroll
  for (int c = 0; c < 2; ++c)
#pragma unroll
    for (int ci = 0; ci < 8; ++ci) {
      dwk0[c][ci] = dw[((c * 8 + ci) * 2 + 0) * 2 + kh];
      dwk1[c][ci] = dw[((c * 8 + ci) * 2 + 1) * 2 + kh];
    }
  float db0 = db[0], db1 = db[1];
  float cw00 = cw[0], cw01 = cw[1], cw10 = cw[2], cw11 = cw[3];
  float cb0 = cb[0], cb1 = cb[1];

  int t0 = chunk * 44;
  int t1 = (t0 + 44 < TO) ? t0 + 44 : TO;   // last chunk: 40
  int tw = (t0 - 16 > 0) ? t0 - 16 : 0;     // 16-step LIF2 warm-up (even)

  const signed char* dbase = d8 + (((long)b * T) * HW + h * 64 + wp) * C1;
  const long tstride = (long)HW * C1;       // bytes per t
  float* outb = out + ((long)b * 2 * HO) * (long)(WO * TO);

  float y0 = 0.0f, y1 = 0.0f;
  uint2 dc = *reinterpret_cast<const uint2*>(dbase + (long)(tw >> 1) * tstride);
  for (int tp = tw; tp < t1; tp += 2) {
    int tn = (tp + 2 < t1) ? ((tp + 2) >> 1) : ((t1 - 1) >> 1);
    uint2 dn = *reinterpret_cast<const uint2*>(dbase + (long)tn * tstride);

    float dv[8];
#pragma unroll
    for (int ci = 0; ci < 4; ++ci) {
      dv[ci]     = (float)(signed char)((dc.x >> (8 * ci)) & 0xff);
      dv[ci + 4] = (float)(signed char)((dc.y >> (8 * ci)) & 0xff);
    }

#pragma unroll
    for (int par = 0; par < 2; ++par) {     // par=0: tp (kt=1), par=1: tp+1 (kt=0)
      int tpp = tp + par;
      float v0 = db0, v1 = db1;
      if (par == 0) {
#pragma unroll
        for (int ci = 0; ci < 8; ++ci) {
          v0 = fmaf(dv[ci], dwk1[0][ci], v0);
          v1 = fmaf(dv[ci], dwk1[1][ci], v1);
        }
      } else {
#pragma unroll
        for (int ci = 0; ci < 8; ++ci) {
          v0 = fmaf(dv[ci], dwk0[0][ci], v0);
          v1 = fmaf(dv[ci], dwk0[1][ci], v1);
        }
      }
      v0 = fmaxf(v0, 0.0f);
      v1 = fmaxf(v1, 0.0f);
      float u0 = fmaf(cw00, v0, fmaf(cw01, v1, cb0));
      float u1 = fmaf(cw10, v0, fmaf(cw11, v1, cb1));
      y0 = fmaf(DEC, y0, u0);
      y1 = fmaf(DEC, y1, u1);
      float s0 = (y0 >= 1.0f) ? 1.0f : 0.0f;
      float s1 = (y1 >= 1.0f) ? 1.0f : 0.0f;
      y0 = (s0 != 0.0f) ? 0.0f : y0;
      y1 = (s1 != 0.0f) ? 0.0f : y1;

      if (tpp >= t0) {
        int k = (tpp - t0) & 15;
        SB[0][wp][k] = s0;
        SB[1][wp][k] = s1;
        if (par == 1 && (k == 15 || tpp == t1 - 1)) {
          __syncthreads();
          int Kc  = k + 1;                  // 16 or a multiple of 4
          int t0f = tpp - k;
#pragma unroll
          for (int o = 0; o < 2; ++o) {
            float* ob = outb + ((long)(o * HO + hp)) * (long)(WO * TO);
#pragma unroll
            for (int i = 0; i < 4; ++i) {
              int idx = (i << 6) + wp;
              int r   = idx >> 2;
              int c   = (idx & 3) << 2;
              if (c < Kc) {
                float4 vv;
                vv.x = SB[o][r][c + 0];
                vv.y = SB[o][r][c + 1];
                vv.z = SB[o][r][c + 2];
                vv.w = SB[o][r][c + 3];
                *reinterpret_cast<float4*>(ob + (long)r * TO + (t0f + c)) = vv;
              }
            }
          }
          __syncthreads();
        }
      }
    }
    dc = dn;
  }
}

// ---------------------------------------------------------------------------
extern "C" void kernel_launch(void* const* d_in, const int* in_sizes, int n_in,
                              void* d_out, int out_size, void* d_ws, size_t ws_size,
                              hipStream_t stream) {
  const float* x  = (const float*)d_in[0];
  const float* w1 = (const float*)d_in[1];
  const float* b1 = (const float*)d_in[2];
  const float* dw = (const float*)d_in[3];
  const float* db = (const float*)d_in[4];
  const float* cw = (const float*)d_in[5];
  const float* cb = (const float*)d_in[6];
  float* out = (float*)d_out;

  float* xT = (float*)d_ws;                                   // 22.94 MB
  signed char* d8 = (signed char*)d_ws + (size_t)B * CIN * T * HW * 4;  // +22.94 MB

  // 1) transpose x -> xT
  transpose_kernel<<<dim3(B * CIN * H * 6), dim3(256), 0, stream>>>(x, xT);
  // 2) conv1+relu+LIF1+delta -> d8 (6 T-chunks, S=5 LDS pipeline)
  convlif_kernel<<<dim3(B * H * 6), dim3(512), 0, stream>>>(xT, w1, b1, d8);
  // 3) deconv+relu+conv2+LIF2 -> out (16 T'-chunks, uint2 prefetch)
  stage2_kernel<<<dim3(B * HO * 16), dim3(64), 0, stream>>>(d8, dw, db, cw, cb, out);
}

// Round 9
// 120.081 us; speedup vs baseline: 10.8477x; 1.0936x over previous
//
#include <hip/hip_runtime.h>

// Sizes (fixed for this problem)
constexpr int B  = 2,  CIN = 2,  H = 64, W = 64, T = 350;
constexpr int C1 = 8;                       // conv1 out channels
constexpr int TO = 700, HO = 128, WO = 64;
constexpr int HW = H * W;                   // 4096

#define DEC 0.05000000074505806f            // (float)(1.0 - 0.95)

// ---------------------------------------------------------------------------
// Kernel 0: transpose x [B,2,H,W,T] -> xT [B,2,T,H,W] so conv reads coalesce.
// ---------------------------------------------------------------------------
__global__ void __launch_bounds__(256) transpose_kernel(
    const float* __restrict__ x, float* __restrict__ xT) {
  __shared__ float tile[64][65];
  int bid   = blockIdx.x;
  int tTile = bid % 6;            // 6 tiles of 64 cover T=350
  int slice = bid / 6;            // (b*2+ci)*64 + h
  int h  = slice % H;
  int bc = slice / H;             // b*2+ci
  int t0 = tTile * 64;
  int tx = threadIdx.x & 63;
  int tz = threadIdx.x >> 6;      // 0..3

  const float* src = x + ((long)bc * H + h) * (long)(W * T);
#pragma unroll
  for (int i = 0; i < 16; ++i) {
    int w = tz * 16 + i;
    int t = t0 + tx;
    tile[w][tx] = (t < T) ? src[(long)w * T + t] : 0.0f;
  }
  __syncthreads();
  float* dst = xT + ((long)bc * T) * HW + h * 64;
#pragma unroll
  for (int i = 0; i < 16; ++i) {
    int tl = tz * 16 + i;
    int t  = t0 + tl;
    if (t < T) dst[(long)t * HW + tx] = tile[tx][tl];
  }
}

// ---------------------------------------------------------------------------
// async global->LDS, 16 bytes per lane (wave-uniform LDS base + lane*16)
// ---------------------------------------------------------------------------
__device__ __forceinline__ void gload_lds16(const float* g, float* l) {
  __builtin_amdgcn_global_load_lds(
      (const __attribute__((address_space(1))) unsigned int*)g,
      (__attribute__((address_space(3))) unsigned int*)l, 16, 0, 0);
}

// ---------------------------------------------------------------------------
// Kernel A: conv1(5x5 over T,H) + bias + relu + LIF1 + delta -> d8 int8
// d8 layout: [b][t][hw][ci]. block = 512 = (co 0..7) x (w 0..63);
// grid (b,h,chunk of 8) = 1024.
// Register economy redesign (r8 was 76 VGPR -> 2 waves/SIMD band):
//  - co = readfirstlane -> all 50 conv weights + bias in SGPRs (no VGPR cap!)
//  - 4-slot sliding window (40 VGPR) + same-step fresh LDS read of tau=t+2
//  - superstep S=8, slots mod 4 (ts multiple of 16 -> static indices)
// LDS: 2 x 96-row staging buffers (3 issues x 32 rows, pad rows in-buffer)
// + single st[8][512] spike staging = 52 KB -> 3 blocks/CU possible.
// Flush of st happens between vmcnt and barrier2 (reads complete in-order
// before the thread's store issues; publication was at barrier1).
// ---------------------------------------------------------------------------
__global__ void __launch_bounds__(512) convlif_kernel(
    const float* __restrict__ xT, const float* __restrict__ w1,
    const float* __restrict__ b1, signed char* __restrict__ d8) {
  __shared__ float buf[2][96 * 64];                   // 2 x 24 KiB
  __shared__ __align__(16) unsigned char st[8][512];  // 4 KiB spike staging
  const int tid = threadIdx.x;
  const int bid = blockIdx.x;
  const int chunk = bid & 7;
  const int rest  = bid >> 3;
  const int h = rest & 63;
  const int b = rest >> 6;
  const int w  = tid & 63;
  const int co = __builtin_amdgcn_readfirstlane(tid >> 6);  // wave-uniform

  // chunk c of 8: stored [48c, min(48c+48,350)); 16-step warm-up before.
  const int tstore = chunk * 48;
  const int ts     = chunk ? tstore - 16 : 0;   // multiple of 16
  const int te     = tstore + 48 < T ? tstore + 48 : T;
  const int nsup   = (te - ts + 7) / 8;

  // Weights (scalar: co,h uniform) + 4-slot window init (taus ts-2..ts+1).
  float wt[2][5][5];
  float win[2][5][4];
#pragma unroll
  for (int ci = 0; ci < 2; ++ci)
#pragma unroll
    for (int dh = 0; dh < 5; ++dh) {
      int hh = h + dh - 2;
      bool hv = (hh >= 0) && (hh < H);
      int hc = hh < 0 ? 0 : (hh > H - 1 ? H - 1 : hh);
#pragma unroll
      for (int dt = 0; dt < 5; ++dt)
        wt[ci][dt][dh] = hv ? w1[((co * 2 + ci) * 5 + dt) * 5 + dh] : 0.0f;
      const float* bp = xT + ((long)((b * 2 + ci) * T)) * HW + hc * 64 + w;
      win[ci][dh][2] = (ts >= 2) ? bp[(long)(ts - 2) * HW] : 0.0f;  // tau ts-2
      win[ci][dh][3] = (ts >= 1) ? bp[(long)(ts - 1) * HW] : 0.0f;  // tau ts-1
      win[ci][dh][0] = bp[(long)(ts + 0) * HW];                      // tau ts
      win[ci][dh][1] = bp[(long)(ts + 1) * HW];                      // tau ts+1
    }
  float bias = b1[co];

  // Staging descriptors: 3 issues x 32 rows; row r -> (j=tau_loc, ci, dh).
  // Packed: cdesc = cpart | (j << 27). cpart < 2^23. j in [0,7].
  int cdesc[3];
#pragma unroll
  for (int i = 0; i < 3; ++i) {
    int r = (tid >> 4) + 32 * i;
    if (r > 79) r = 79;                     // clamp SOURCE only (rows 80..95 pad)
    int j   = r / 10;
    int rem = r - j * 10;
    int ci  = rem / 5;
    int dh  = rem - ci * 5;
    int hh = h + dh - 2;
    int hc = hh < 0 ? 0 : (hh > H - 1 ? H - 1 : hh);
    cdesc[i] = (((b * 2 + ci) * T) * HW + hc * 64 + (tid & 15) * 4) | (j << 27);
  }

  // Prologue: stage buffer 0 (taus ts+2 .. ts+9).
#pragma unroll
  for (int i = 0; i < 3; ++i) {
    int tau = ts + 2 + (cdesc[i] >> 27);
    if (tau > T - 1) tau = T - 1;
    gload_lds16(xT + (long)(cdesc[i] & 0x07ffffff) + (long)tau * HW,
                &buf[0][((i * 32 + co * 4) & 127) * 64 + (i * 32 + co * 4 >= 128 ? 0 : 0)]);
  }

  asm volatile("s_waitcnt vmcnt(0)" ::: "memory");
  __builtin_amdgcn_s_barrier();
  asm volatile("" ::: "memory");

  signed char* const d8row = d8 + ((long)(b * T)) * (HW * C1) + h * 512;
  const int fl_u  = tid >> 5;               // flush row (0..7) for tid<256
  const int fl_cb = (tid & 31) * 16;        // flush byte offset within row
  const int stw   = w * 8 + co;             // this thread's spike byte slot

  float y = 0.0f, sprev = 0.0f;
  for (int k = 0; k < nsup; ++k) {
    // barrier1: publish st writes of superstep k-1; buf[(k+1)&1] readers done
    asm volatile("s_waitcnt lgkmcnt(0)" ::: "memory");
    __builtin_amdgcn_s_barrier();
    asm volatile("" ::: "memory");

    if (k + 1 < nsup) {
      int bs = ts + 2 + 8 * (k + 1);
      float* nb = &buf[(k + 1) & 1][0];
#pragma unroll
      for (int i = 0; i < 3; ++i) {
        int tau = bs + (cdesc[i] >> 27);
        if (tau > T - 1) tau = T - 1;
        gload_lds16(xT + (long)(cdesc[i] & 0x07ffffff) + (long)tau * HW,
                    nb + (i * 32 + co * 4) * 64);
      }
      asm volatile("s_waitcnt vmcnt(3)" ::: "memory");   // buf[k&1] retired
    } else {
      asm volatile("s_waitcnt vmcnt(0)" ::: "memory");
    }

    // Flush superstep k-1's spikes (published at barrier1; single st buffer:
    // the per-thread LDS read completes before this thread's store issues,
    // so reaching barrier2 implies the slot is free for compute-k rewrites).
    if (k > 0 && tid < 256) {
      int t = ts + 8 * (k - 1) + fl_u;
      if (t >= tstore && t < te) {
        uint4 v = *reinterpret_cast<const uint4*>(&st[fl_u][fl_cb]);
        *reinterpret_cast<uint4*>(d8row + (long)t * (HW * C1) + fl_cb) = v;
      }
    }

    asm volatile("s_waitcnt lgkmcnt(0)" ::: "memory");
    __builtin_amdgcn_s_barrier();           // barrier2: buf[k&1] ready, st free
    asm volatile("" ::: "memory");

    float* lb = &buf[k & 1][0];
    {
      // zero rows whose tau >= T (only final supersteps of last chunk)
      int bufstart = ts + 2 + 8 * k;        // first tau in this buffer
      int rz0 = (T - bufstart) * 10;
      if (rz0 < 80) {
        if (rz0 < 0) rz0 = 0;
        for (int r = rz0 + co; r < 80; r += 8) lb[r * 64 + w] = 0.0f;
        asm volatile("s_waitcnt lgkmcnt(0)" ::: "memory");
        __builtin_amdgcn_s_barrier();
        asm volatile("" ::: "memory");
      }
    }

    const int t0s = ts + 8 * k;
#pragma unroll
    for (int u = 0; u < 8; ++u) {
      int t = t0s + u;
      // fresh read: tau = t+2 lives at LDS row (u*10 + ci*5 + dh)
      float fr[2][5];
#pragma unroll
      for (int ci = 0; ci < 2; ++ci)
#pragma unroll
        for (int dh = 0; dh < 5; ++dh)
          fr[ci][dh] = lb[(u * 10 + ci * 5 + dh) * 64 + w];

      float ac0 = 0.f, ac1 = 0.f, ac2 = 0.f, ac3 = 0.f;
#pragma unroll
      for (int ci = 0; ci < 2; ++ci)
#pragma unroll
        for (int dt = 0; dt < 5; ++dt)
#pragma unroll
          for (int dh = 0; dh < 5; ++dh) {
            const int q = (ci * 25 + dt * 5 + dh) & 3;
            // tau = t-2+dt: dt<4 -> window slot (u+2+dt)&3; dt==4 -> fresh
            float tap = (dt < 4) ? win[ci][dh][(u + 2 + dt) & 3] : fr[ci][dh];
            float p = tap * wt[ci][dt][dh];
            if (q == 0) ac0 += p;
            else if (q == 1) ac1 += p;
            else if (q == 2) ac2 += p;
            else ac3 += p;
          }
      float a = ((ac0 + ac1) + (ac2 + ac3)) + bias;
      a = fmaxf(a, 0.0f);
      y = fmaf(DEC, y, a);
      float s = (y >= 1.0f) ? 1.0f : 0.0f;
      float dlt = (t == 0) ? 0.0f : (s - sprev);
      st[u][stw] = (unsigned char)(signed char)dlt;
      sprev = s;
      y = (s != 0.0f) ? 0.0f : y;
      // window advance: fresh tau t+2 replaces old t-2 at slot (u+2)&3
#pragma unroll
      for (int ci = 0; ci < 2; ++ci)
#pragma unroll
        for (int dh = 0; dh < 5; ++dh)
          win[ci][dh][(u + 2) & 3] = fr[ci][dh];
    }
  }

  // Epilogue flush: last superstep's spikes.
  asm volatile("s_waitcnt lgkmcnt(0)" ::: "memory");
  __builtin_amdgcn_s_barrier();
  asm volatile("" ::: "memory");
  if (tid < 256) {
    int t = ts + 8 * (nsup - 1) + fl_u;
    if (t >= tstore && t < te) {
      uint4 v = *reinterpret_cast<const uint4*>(&st[fl_u][fl_cb]);
      *reinterpret_cast<uint4*>(d8row + (long)t * (HW * C1) + fl_cb) = v;
    }
  }
}

// ---------------------------------------------------------------------------
// Kernel B: deconv(2x2,s2) + bias + relu + conv2(1x1) + LIF2 -> out
// d8 [b][t][hw][ci]: one 8B uint2 load per pair-step, prefetched 1 iter ahead.
// out layout [B,2,H',W',T']; LDS-staged transposed flush. 16 chunks.
// (unchanged -- passed rounds 5-8)
// ---------------------------------------------------------------------------
__global__ void __launch_bounds__(64) stage2_kernel(
    const signed char* __restrict__ d8, const float* __restrict__ dw,
    const float* __restrict__ db, const float* __restrict__ cw,
    const float* __restrict__ cb, float* __restrict__ out) {
  __shared__ float SB[2][64][17];
  int bid   = blockIdx.x;
  int chunk = bid & 15;           // 16 chunks over T'=700
  int rest  = bid >> 4;
  int hp = rest & 127;            // h'
  int b  = rest >> 7;
  int wp = threadIdx.x;           // w'

  int h  = hp >> 1;
  int kh = 1 - (hp & 1);

  float dwk0[2][8], dwk1[2][8];
#pragma unroll
  for (int c = 0; c < 2; ++c)
#pragma unroll
    for (int ci = 0; ci < 8; ++ci) {
      dwk0[c][ci] = dw[((c * 8 + ci) * 2 + 0) * 2 + kh];
      dwk1[c][ci] = dw[((c * 8 + ci) * 2 + 1) * 2 + kh];
    }
  float db0 = db[0], db1 = db[1];
  float cw00 = cw[0], cw01 = cw[1], cw10 = cw[2], cw11 = cw[3];
  float cb0 = cb[0], cb1 = cb[1];

  int t0 = chunk * 44;
  int t1 = (t0 + 44 < TO) ? t0 + 44 : TO;   // last chunk: 40
  int tw = (t0 - 16 > 0) ? t0 - 16 : 0;     // 16-step LIF2 warm-up (even)

  const signed char* dbase = d8 + (((long)b * T) * HW + h * 64 + wp) * C1;
  const long tstride = (long)HW * C1;       // bytes per t
  float* outb = out + ((long)b * 2 * HO) * (long)(WO * TO);

  float y0 = 0.0f, y1 = 0.0f;
  uint2 dc = *reinterpret_cast<const uint2*>(dbase + (long)(tw >> 1) * tstride);
  for (int tp = tw; tp < t1; tp += 2) {
    int tn = (tp + 2 < t1) ? ((tp + 2) >> 1) : ((t1 - 1) >> 1);
    uint2 dn = *reinterpret_cast<const uint2*>(dbase + (long)tn * tstride);

    float dv[8];
#pragma unroll
    for (int ci = 0; ci < 4; ++ci) {
      dv[ci]     = (float)(signed char)((dc.x >> (8 * ci)) & 0xff);
      dv[ci + 4] = (float)(signed char)((dc.y >> (8 * ci)) & 0xff);
    }

#pragma unroll
    for (int par = 0; par < 2; ++par) {     // par=0: tp (kt=1), par=1: tp+1 (kt=0)
      int tpp = tp + par;
      float v0 = db0, v1 = db1;
      if (par == 0) {
#pragma unroll
        for (int ci = 0; ci < 8; ++ci) {
          v0 = fmaf(dv[ci], dwk1[0][ci], v0);
          v1 = fmaf(dv[ci], dwk1[1][ci], v1);
        }
      } else {
#pragma unroll
        for (int ci = 0; ci < 8; ++ci) {
          v0 = fmaf(dv[ci], dwk0[0][ci], v0);
          v1 = fmaf(dv[ci], dwk0[1][ci], v1);
        }
      }
      v0 = fmaxf(v0, 0.0f);
      v1 = fmaxf(v1, 0.0f);
      float u0 = fmaf(cw00, v0, fmaf(cw01, v1, cb0));
      float u1 = fmaf(cw10, v0, fmaf(cw11, v1, cb1));
      y0 = fmaf(DEC, y0, u0);
      y1 = fmaf(DEC, y1, u1);
      float s0 = (y0 >= 1.0f) ? 1.0f : 0.0f;
      float s1 = (y1 >= 1.0f) ? 1.0f : 0.0f;
      y0 = (s0 != 0.0f) ? 0.0f : y0;
      y1 = (s1 != 0.0f) ? 0.0f : y1;

      if (tpp >= t0) {
        int k = (tpp - t0) & 15;
        SB[0][wp][k] = s0;
        SB[1][wp][k] = s1;
        if (par == 1 && (k == 15 || tpp == t1 - 1)) {
          __syncthreads();
          int Kc  = k + 1;                  // 16 or a multiple of 4
          int t0f = tpp - k;
#pragma unroll
          for (int o = 0; o < 2; ++o) {
            float* ob = outb + ((long)(o * HO + hp)) * (long)(WO * TO);
#pragma unroll
            for (int i = 0; i < 4; ++i) {
              int idx = (i << 6) + wp;
              int r   = idx >> 2;
              int c   = (idx & 3) << 2;
              if (c < Kc) {
                float4 vv;
                vv.x = SB[o][r][c + 0];
                vv.y = SB[o][r][c + 1];
                vv.z = SB[o][r][c + 2];
                vv.w = SB[o][r][c + 3];
                *reinterpret_cast<float4*>(ob + (long)r * TO + (t0f + c)) = vv;
              }
            }
          }
          __syncthreads();
        }
      }
    }
    dc = dn;
  }
}

// ---------------------------------------------------------------------------
extern "C" void kernel_launch(void* const* d_in, const int* in_sizes, int n_in,
                              void* d_out, int out_size, void* d_ws, size_t ws_size,
                              hipStream_t stream) {
  const float* x  = (const float*)d_in[0];
  const float* w1 = (const float*)d_in[1];
  const float* b1 = (const float*)d_in[2];
  const float* dw = (const float*)d_in[3];
  const float* db = (const float*)d_in[4];
  const float* cw = (const float*)d_in[5];
  const float* cb = (const float*)d_in[6];
  float* out = (float*)d_out;

  float* xT = (float*)d_ws;                                   // 22.94 MB
  signed char* d8 = (signed char*)d_ws + (size_t)B * CIN * T * HW * 4;  // +22.94 MB

  // 1) transpose x -> xT
  transpose_kernel<<<dim3(B * CIN * H * 6), dim3(256), 0, stream>>>(x, xT);
  // 2) conv1+relu+LIF1+delta -> d8 (8 T-chunks, S=8, scalar weights)
  convlif_kernel<<<dim3(B * H * 8), dim3(512), 0, stream>>>(xT, w1, b1, d8);
  // 3) deconv+relu+conv2+LIF2 -> out (16 T'-chunks, uint2 prefetch)
  stage2_kernel<<<dim3(B * HO * 16), dim3(64), 0, stream>>>(d8, dw, db, cw, cb, out);
}